// Round 13
// baseline (189.633 us; speedup 1.0000x reference)
//
#include <hip/hip_runtime.h>
#include <math.h>

// B=16, C=64, H=W=112, WS=7 -> 784 tiles of 16x16 pixels
#define CC    64
#define CF    16
#define NPIX  256
#define KK    9
#define HWQ   12544
#define WWQ   112
#define NTILE 784
#define NROWS (NTILE * NPIX)   // 200704

// ============================================================
// Kernel 1: per-pixel features f = Wf@x + bf, normalize.
// ============================================================
__global__ __launch_bounds__(64, 4) void feat_k(
    const float* __restrict__ x_in, const float* __restrict__ Wf,
    const float* __restrict__ bf,
    float* __restrict__ xn_g, float* __restrict__ nrm_g)
{
    __shared__ float s_Wt[CC * CF];   // transposed [c][o]
    __shared__ float s_bf[CF];
    const int tid = threadIdx.x;
    for (int idx = tid; idx < CC * CF; idx += 64) {
        int c = idx >> 4, o = idx & 15;
        s_Wt[idx] = Wf[o * CC + c];
    }
    if (tid < CF) s_bf[tid] = bf[tid];
    __syncthreads();

    const int p    = blockIdx.x * 64 + tid;
    const int tile = p >> 8, pix = p & 255;
    const int bb = tile / 49, ssb = tile % 49;
    const int s1 = ssb / 7, s2 = ssb % 7;
    const int gy = s1 * 16 + (pix >> 4), gx = s2 * 16 + (pix & 15);
    const float* xb = x_in + (size_t)bb * CC * HWQ + (size_t)gy * WWQ + gx;

    float fv[CF];
    #pragma unroll
    for (int o = 0; o < CF; ++o) fv[o] = 0.0f;
    #pragma unroll 8
    for (int c = 0; c < CC; ++c) {
        float xv = xb[(size_t)c * HWQ];
        const float4* w4 = reinterpret_cast<const float4*>(&s_Wt[c << 4]);
        float4 w0 = w4[0], w1 = w4[1], w2 = w4[2], w3 = w4[3];
        fv[0]  = fmaf(xv, w0.x, fv[0]);  fv[1]  = fmaf(xv, w0.y, fv[1]);
        fv[2]  = fmaf(xv, w0.z, fv[2]);  fv[3]  = fmaf(xv, w0.w, fv[3]);
        fv[4]  = fmaf(xv, w1.x, fv[4]);  fv[5]  = fmaf(xv, w1.y, fv[5]);
        fv[6]  = fmaf(xv, w1.z, fv[6]);  fv[7]  = fmaf(xv, w1.w, fv[7]);
        fv[8]  = fmaf(xv, w2.x, fv[8]);  fv[9]  = fmaf(xv, w2.y, fv[9]);
        fv[10] = fmaf(xv, w2.z, fv[10]); fv[11] = fmaf(xv, w2.w, fv[11]);
        fv[12] = fmaf(xv, w3.x, fv[12]); fv[13] = fmaf(xv, w3.y, fv[13]);
        fv[14] = fmaf(xv, w3.z, fv[14]); fv[15] = fmaf(xv, w3.w, fv[15]);
    }
    #pragma unroll
    for (int o = 0; o < CF; ++o) fv[o] += s_bf[o];

    float ss2 = 0.0f;
    #pragma unroll
    for (int o = 0; o < CF; ++o) ss2 = fmaf(fv[o], fv[o], ss2);
    float nrm = fmaxf(sqrtf(ss2), 1e-8f);

    float xn[CF];
    #pragma unroll
    for (int o = 0; o < CF; ++o) xn[o] = fv[o] / nrm;

    float4* dst = reinterpret_cast<float4*>(xn_g + (size_t)p * CF);
    dst[0] = make_float4(xn[0],  xn[1],  xn[2],  xn[3]);
    dst[1] = make_float4(xn[4],  xn[5],  xn[6],  xn[7]);
    dst[2] = make_float4(xn[8],  xn[9],  xn[10], xn[11]);
    dst[3] = make_float4(xn[12], xn[13], xn[14], xn[15]);
    nrm_g[p] = nrm;
}

// ---------------- shared scan machinery ----------------
#define DOT16(dot, X, a0, a1, a2, a3)                                \
    dot = fmaf(X[0],  (a0).x, dot); dot = fmaf(X[1],  (a0).y, dot);  \
    dot = fmaf(X[2],  (a0).z, dot); dot = fmaf(X[3],  (a0).w, dot);  \
    dot = fmaf(X[4],  (a1).x, dot); dot = fmaf(X[5],  (a1).y, dot);  \
    dot = fmaf(X[6],  (a1).z, dot); dot = fmaf(X[7],  (a1).w, dot);  \
    dot = fmaf(X[8],  (a2).x, dot); dot = fmaf(X[9],  (a2).y, dot);  \
    dot = fmaf(X[10], (a2).z, dot); dot = fmaf(X[11], (a2).w, dot);  \
    dot = fmaf(X[12], (a3).x, dot); dot = fmaf(X[13], (a3).y, dot);  \
    dot = fmaf(X[14], (a3).z, dot); dot = fmaf(X[15], (a3).w, dot);

// guard-free sorted top-9 insert on suffixed state (tv0S..tv8S / ti0S..ti8S);
// strict '>' keeps lower index on ties, matching lax.top_k.
#define TOP9_INS(S, cv, ci) {                                        \
    const bool g0 = (cv) > tv0##S; const bool g1 = (cv) > tv1##S;    \
    const bool g2 = (cv) > tv2##S; const bool g3 = (cv) > tv3##S;    \
    const bool g4 = (cv) > tv4##S; const bool g5 = (cv) > tv5##S;    \
    const bool g6 = (cv) > tv6##S; const bool g7 = (cv) > tv7##S;    \
    const bool g8 = (cv) > tv8##S;                                   \
    const float nv0 = g0 ? (cv) : tv0##S;                            \
    const float nv1 = __builtin_amdgcn_fmed3f((cv), tv0##S, tv1##S); \
    const float nv2 = __builtin_amdgcn_fmed3f((cv), tv1##S, tv2##S); \
    const float nv3 = __builtin_amdgcn_fmed3f((cv), tv2##S, tv3##S); \
    const float nv4 = __builtin_amdgcn_fmed3f((cv), tv3##S, tv4##S); \
    const float nv5 = __builtin_amdgcn_fmed3f((cv), tv4##S, tv5##S); \
    const float nv6 = __builtin_amdgcn_fmed3f((cv), tv5##S, tv6##S); \
    const float nv7 = __builtin_amdgcn_fmed3f((cv), tv6##S, tv7##S); \
    const float nv8 = __builtin_amdgcn_fmed3f((cv), tv7##S, tv8##S); \
    const int nt0 = g0 ? (ci) : ti0##S;                              \
    const int nt1 = g0 ? ti0##S : (g1 ? (ci) : ti1##S);              \
    const int nt2 = g1 ? ti1##S : (g2 ? (ci) : ti2##S);              \
    const int nt3 = g2 ? ti2##S : (g3 ? (ci) : ti3##S);              \
    const int nt4 = g3 ? ti3##S : (g4 ? (ci) : ti4##S);              \
    const int nt5 = g4 ? ti4##S : (g5 ? (ci) : ti5##S);              \
    const int nt6 = g5 ? ti5##S : (g6 ? (ci) : ti6##S);              \
    const int nt7 = g6 ? ti6##S : (g7 ? (ci) : ti7##S);              \
    const int nt8 = g7 ? ti7##S : (g8 ? (ci) : ti8##S);              \
    tv0##S = nv0; tv1##S = nv1; tv2##S = nv2; tv3##S = nv3;          \
    tv4##S = nv4; tv5##S = nv5; tv6##S = nv6; tv7##S = nv7;          \
    tv8##S = nv8;                                                    \
    ti0##S = nt0; ti1##S = nt1; ti2##S = nt2; ti3##S = nt3;          \
    ti4##S = nt4; ti5##S = nt5; ti6##S = nt6; ti7##S = nt7;          \
    ti8##S = nt8; }

// one candidate, two rows (A,B): 4 ds_read_b128 feed 2 dots.
#define SIM_ITER2(MJ) {                                              \
    const int lm = lmbase + (MJ);                                    \
    const float4* xm4 =                                              \
        reinterpret_cast<const float4*>(&s_xn[gmbase + (MJ)][0]);    \
    const float4 a0 = xm4[0], a1 = xm4[1], a2 = xm4[2], a3 = xm4[3]; \
    float dotA = 0.0f, dotB = 0.0f;                                  \
    DOT16(dotA, xnrA, a0, a1, a2, a3);                               \
    DOT16(dotB, xnrB, a0, a1, a2, a3);                               \
    const int dj = pj - (MJ);                                        \
    const int dj2 = dj * dj;                                         \
    const float sA = s_tabA[d2iA + dj2];                             \
    const float sB = s_tabA[d2iB + dj2];                             \
    const float combA = __fadd_rn(__fmul_rn(alpha, dotA), sA);       \
    const float combB = __fadd_rn(__fmul_rn(alpha, dotB), sB);       \
    TOP9_INS(A, combA, lm)                                           \
    TOP9_INS(B, combB, lm) }

#define SIM_ROW16_2()                                                \
        SIM_ITER2(0)  SIM_ITER2(1)  SIM_ITER2(2)  SIM_ITER2(3)       \
        SIM_ITER2(4)  SIM_ITER2(5)  SIM_ITER2(6)  SIM_ITER2(7)       \
        SIM_ITER2(8)  SIM_ITER2(9)  SIM_ITER2(10) SIM_ITER2(11)      \
        SIM_ITER2(12) SIM_ITER2(13) SIM_ITER2(14) SIM_ITER2(15)

// publish both rows' sorted partials into the single slot (u16 idx)
#define PUBLISH_AB() {                                               \
    s_pv[0][0][l64]=tv0A; s_pi[0][0][l64]=(unsigned short)ti0A;      \
    s_pv[0][1][l64]=tv1A; s_pi[0][1][l64]=(unsigned short)ti1A;      \
    s_pv[0][2][l64]=tv2A; s_pi[0][2][l64]=(unsigned short)ti2A;      \
    s_pv[0][3][l64]=tv3A; s_pi[0][3][l64]=(unsigned short)ti3A;      \
    s_pv[0][4][l64]=tv4A; s_pi[0][4][l64]=(unsigned short)ti4A;      \
    s_pv[0][5][l64]=tv5A; s_pi[0][5][l64]=(unsigned short)ti5A;      \
    s_pv[0][6][l64]=tv6A; s_pi[0][6][l64]=(unsigned short)ti6A;      \
    s_pv[0][7][l64]=tv7A; s_pi[0][7][l64]=(unsigned short)ti7A;      \
    s_pv[0][8][l64]=tv8A; s_pi[0][8][l64]=(unsigned short)ti8A;      \
    s_pv[1][0][l64]=tv0B; s_pi[1][0][l64]=(unsigned short)ti0B;      \
    s_pv[1][1][l64]=tv1B; s_pi[1][1][l64]=(unsigned short)ti1B;      \
    s_pv[1][2][l64]=tv2B; s_pi[1][2][l64]=(unsigned short)ti2B;      \
    s_pv[1][3][l64]=tv3B; s_pi[1][3][l64]=(unsigned short)ti3B;      \
    s_pv[1][4][l64]=tv4B; s_pi[1][4][l64]=(unsigned short)ti4B;      \
    s_pv[1][5][l64]=tv5B; s_pi[1][5][l64]=(unsigned short)ti5B;      \
    s_pv[1][6][l64]=tv6B; s_pi[1][6][l64]=(unsigned short)ti6B;      \
    s_pv[1][7][l64]=tv7B; s_pi[1][7][l64]=(unsigned short)ti7B;      \
    s_pv[1][8][l64]=tv8B; s_pi[1][8][l64]=(unsigned short)ti8B; }

#define MERGE_AB() {                                                 \
    _Pragma("unroll")                                                \
    for (int k = 0; k < KK; ++k) {                                   \
        const float bvA = s_pv[0][k][l64];                           \
        const int   biA = (int)s_pi[0][k][l64];                      \
        TOP9_INS(A, bvA, biA)                                        \
        const float bvB = s_pv[1][k][l64];                           \
        const int   biB = (int)s_pi[1][k][l64];                      \
        TOP9_INS(B, bvB, biB)                                        \
    } }

// full per-row epilogue: edge MLP + aggregate + project + store
#define EPILOGUE(TV, TI, PI, PJ) {                                   \
    float wk[KK]; float wsum = 0.0f;                                 \
    _Pragma("unroll")                                                \
    for (int k = 0; k < KK; ++k) {                                   \
        int m = TI[k];                                               \
        int di = (PI) - (m >> 4);                                    \
        int dj = (PJ) - (m & 15);                                    \
        float sd = s_tab[di * di + dj * dj];                         \
        float sf = (TV[k] - __fmul_rn(oma, sd)) / alpha;             \
        float hsum = b2r;                                            \
        _Pragma("unroll")                                            \
        for (int h = 0; h < 4; ++h) {                                \
            float z  = fmaf(sf, W1r[2*h], fmaf(sd, W1r[2*h+1], b1r[h])); \
            float sg = 1.0f / (1.0f + expf(-z));                     \
            hsum = fmaf(z * sg, W2r[h], hsum);                       \
        }                                                            \
        float wg = 1.0f / (1.0f + expf(-hsum));                      \
        wk[k] = wg; wsum += wg;                                      \
    }                                                                \
    wsum += 1e-12f;                                                  \
    float outv[CF];                                                  \
    _Pragma("unroll")                                                \
    for (int o = 0; o < CF; ++o) outv[o] = 0.0f;                     \
    _Pragma("unroll")                                                \
    for (int k = 0; k < KK; ++k) {                                   \
        const int m = TI[k];                                         \
        const float wnm = (wk[k] / wsum) * s_nrm[m];                 \
        const float4* xf4 = reinterpret_cast<const float4*>(&s_xn[m][0]); \
        float4 m0 = xf4[0], m1 = xf4[1], m2 = xf4[2], m3 = xf4[3];   \
        outv[0]  = fmaf(wnm, m0.x, outv[0]);  outv[1]  = fmaf(wnm, m0.y, outv[1]);  \
        outv[2]  = fmaf(wnm, m0.z, outv[2]);  outv[3]  = fmaf(wnm, m0.w, outv[3]);  \
        outv[4]  = fmaf(wnm, m1.x, outv[4]);  outv[5]  = fmaf(wnm, m1.y, outv[5]);  \
        outv[6]  = fmaf(wnm, m1.z, outv[6]);  outv[7]  = fmaf(wnm, m1.w, outv[7]);  \
        outv[8]  = fmaf(wnm, m2.x, outv[8]);  outv[9]  = fmaf(wnm, m2.y, outv[9]);  \
        outv[10] = fmaf(wnm, m2.z, outv[10]); outv[11] = fmaf(wnm, m2.w, outv[11]); \
        outv[12] = fmaf(wnm, m3.x, outv[12]); outv[13] = fmaf(wnm, m3.y, outv[13]); \
        outv[14] = fmaf(wnm, m3.z, outv[14]); outv[15] = fmaf(wnm, m3.w, outv[15]); \
    }                                                                \
    const int gy = s1 * 16 + (PI), gx = s2 * 16 + (PJ);              \
    float* yb = y + (size_t)bb * CC * HWQ + (size_t)gy * WWQ + gx;   \
    _Pragma("unroll 4")                                              \
    for (int o = 0; o < CC; ++o) {                                   \
        const float4* w4 = reinterpret_cast<const float4*>(&Wp[o * CF]); \
        float4 w0 = w4[0], w1 = w4[1], w2 = w4[2], w3 = w4[3];       \
        float acc = 0.0f;                                            \
        acc = fmaf(outv[0],  w0.x, acc); acc = fmaf(outv[1],  w0.y, acc); \
        acc = fmaf(outv[2],  w0.z, acc); acc = fmaf(outv[3],  w0.w, acc); \
        acc = fmaf(outv[4],  w1.x, acc); acc = fmaf(outv[5],  w1.y, acc); \
        acc = fmaf(outv[6],  w1.z, acc); acc = fmaf(outv[7],  w1.w, acc); \
        acc = fmaf(outv[8],  w2.x, acc); acc = fmaf(outv[9],  w2.y, acc); \
        acc = fmaf(outv[10], w2.z, acc); acc = fmaf(outv[11], w2.w, acc); \
        acc = fmaf(outv[12], w3.x, acc); acc = fmaf(outv[13], w3.y, acc); \
        acc = fmaf(outv[14], w3.z, acc); acc = fmaf(outv[15], w3.w, acc); \
        yb[(size_t)o * HWQ] = acc + bp[o];                           \
    } }

// ============================================================
// Kernel 2: 2-rows-per-thread, 4-way candidate split, single-slot
// sequential LDS merge (Q0<-Q1<-Q2<-Q3, exact tie semantics).
// Block = 256 threads = 4 waves; LDS 27.3 KB; launch_bounds(256,2)
// (VGPR cap 256 -> no spill, r11-verified).
// ============================================================
__global__ __launch_bounds__(256, 2) void gnn_split(
    const float* __restrict__ xn_g, const float* __restrict__ nrm_g,
    const float* __restrict__ Wp,   const float* __restrict__ bp,
    const float* __restrict__ W1,   const float* __restrict__ b1,
    const float* __restrict__ W2,   const float* __restrict__ b2,
    const float* __restrict__ sigma_p, const float* __restrict__ alpha_p,
    float* __restrict__ y)
{
    __shared__ float s_xn[NPIX][CF];          // 16 KB tile features
    __shared__ float s_nrm[NPIX];             // 1 KB
    __shared__ float s_tab[451];              // raw exp(-d^2/(2 sigma^2))
    __shared__ float s_tabA[451];             // (1-alpha) * table
    __shared__ float s_pv[2][KK][64];         // 4.5 KB slot values [rowA/B]
    __shared__ unsigned short s_pi[2][KK][64];// 2.25 KB slot indices

    const int bid  = blockIdx.x;
    const int tile = bid >> 1;
    const int hlf  = bid & 1;             // which 128-row half of the tile
    const int bb = tile / 49, ssb = tile % 49;
    const int s1 = ssb / 7, s2 = ssb % 7;
    const int tid = threadIdx.x;
    const int l64 = tid & 63;             // row-thread within half
    const int ch  = tid >> 6;             // candidate quarter = wave id

    const float alpha = alpha_p[0];
    const float oma   = 1.0f - alpha;
    const float sig   = sigma_p[0];
    const float denom = 2.0f * sig * sig;

    for (int t = tid; t < 451; t += 256) {
        float dd = sqrtf((float)t);
        float v  = expf((-(dd * dd)) / denom);
        s_tab[t]  = v;
        s_tabA[t] = __fmul_rn(oma, v);
    }
    const float* xt = xn_g + (size_t)tile * NPIX * CF;
    {
        const float4* src = reinterpret_cast<const float4*>(xt);
        float4*       dst = reinterpret_cast<float4*>(&s_xn[0][0]);
        #pragma unroll
        for (int i = 0; i < 4; ++i) dst[tid + i * 256] = src[tid + i * 256];
        s_nrm[tid] = nrm_g[(size_t)tile * NPIX + tid];
    }
    float W1r[8], b1r[4], W2r[4];
    #pragma unroll
    for (int h = 0; h < 8; ++h) W1r[h] = W1[h];
    #pragma unroll
    for (int h = 0; h < 4; ++h) { b1r[h] = b1[h]; W2r[h] = W2[h]; }
    const float b2r = b2[0];
    __syncthreads();

    const int rA  = hlf * 128 + l64;      // rows owned by this thread
    const int rB  = rA + 64;
    const int piA = rA >> 4, piB = rB >> 4;
    const int pj  = rA & 15;              // same for both rows

    float xnrA[CF], xnrB[CF];
    {
        const float4* xa = reinterpret_cast<const float4*>(&s_xn[rA][0]);
        float4 a0 = xa[0], a1 = xa[1], a2 = xa[2], a3 = xa[3];
        xnrA[0]=a0.x;  xnrA[1]=a0.y;  xnrA[2]=a0.z;  xnrA[3]=a0.w;
        xnrA[4]=a1.x;  xnrA[5]=a1.y;  xnrA[6]=a1.z;  xnrA[7]=a1.w;
        xnrA[8]=a2.x;  xnrA[9]=a2.y;  xnrA[10]=a2.z; xnrA[11]=a2.w;
        xnrA[12]=a3.x; xnrA[13]=a3.y; xnrA[14]=a3.z; xnrA[15]=a3.w;
        const float4* xb4 = reinterpret_cast<const float4*>(&s_xn[rB][0]);
        float4 b0 = xb4[0], b1v = xb4[1], b2v = xb4[2], b3 = xb4[3];
        xnrB[0]=b0.x;  xnrB[1]=b0.y;  xnrB[2]=b0.z;  xnrB[3]=b0.w;
        xnrB[4]=b1v.x; xnrB[5]=b1v.y; xnrB[6]=b1v.z; xnrB[7]=b1v.w;
        xnrB[8]=b2v.x; xnrB[9]=b2v.y; xnrB[10]=b2v.z; xnrB[11]=b2v.w;
        xnrB[12]=b3.x; xnrB[13]=b3.y; xnrB[14]=b3.z; xnrB[15]=b3.w;
    }

    float tv0A,tv1A,tv2A,tv3A,tv4A,tv5A,tv6A,tv7A,tv8A;
    int   ti0A,ti1A,ti2A,ti3A,ti4A,ti5A,ti6A,ti7A,ti8A;
    float tv0B,tv1B,tv2B,tv3B,tv4B,tv5B,tv6B,tv7B,tv8B;
    int   ti0B,ti1B,ti2B,ti3B,ti4B,ti5B,ti6B,ti7B,ti8B;
    tv0A=tv1A=tv2A=tv3A=tv4A=tv5A=tv6A=tv7A=tv8A = -INFINITY;
    ti0A=ti1A=ti2A=ti3A=ti4A=ti5A=ti6A=ti7A=ti8A = 0;
    tv0B=tv1B=tv2B=tv3B=tv4B=tv5B=tv6B=tv7B=tv8B = -INFINITY;
    ti0B=ti1B=ti2B=ti3B=ti4B=ti5B=ti6B=ti7B=ti8B = 0;

    // scan this wave's candidate quarter: mi in [ch*4, ch*4+4)
    const int mi0 = ch << 2;
    #pragma unroll 1
    for (int q = 0; q < 4; ++q) {
        const int mi     = mi0 + q;
        const int diA    = piA - mi;
        const int diB    = piB - mi;
        const int d2iA   = diA * diA;
        const int d2iB   = diB * diB;
        const int gmbase = mi << 4;          // global candidate row base
        const int lmbase = q << 4;           // group-local base (0..63)
        SIM_ROW16_2()
    }

    // globalize indices (quarter base)
    {
        const int cb = ch << 6;
        ti0A+=cb; ti1A+=cb; ti2A+=cb; ti3A+=cb; ti4A+=cb;
        ti5A+=cb; ti6A+=cb; ti7A+=cb; ti8A+=cb;
        ti0B+=cb; ti1B+=cb; ti2B+=cb; ti3B+=cb; ti4B+=cb;
        ti5B+=cb; ti6B+=cb; ti7B+=cb; ti8B+=cb;
    }

    // sequential single-slot merges: Q0 <- Q1, Q0 <- Q2, Q0 <- Q3
    if (ch == 1) PUBLISH_AB()
    __syncthreads();
    if (ch == 0) MERGE_AB()
    __syncthreads();
    if (ch == 2) PUBLISH_AB()
    __syncthreads();
    if (ch == 0) MERGE_AB()
    __syncthreads();
    if (ch == 3) PUBLISH_AB()
    __syncthreads();
    if (ch == 0) MERGE_AB()
    __syncthreads();
    // hand row-B state to wave 1 for a parallel epilogue
    if (ch == 0) {
        s_pv[1][0][l64]=tv0B; s_pi[1][0][l64]=(unsigned short)ti0B;
        s_pv[1][1][l64]=tv1B; s_pi[1][1][l64]=(unsigned short)ti1B;
        s_pv[1][2][l64]=tv2B; s_pi[1][2][l64]=(unsigned short)ti2B;
        s_pv[1][3][l64]=tv3B; s_pi[1][3][l64]=(unsigned short)ti3B;
        s_pv[1][4][l64]=tv4B; s_pi[1][4][l64]=(unsigned short)ti4B;
        s_pv[1][5][l64]=tv5B; s_pi[1][5][l64]=(unsigned short)ti5B;
        s_pv[1][6][l64]=tv6B; s_pi[1][6][l64]=(unsigned short)ti6B;
        s_pv[1][7][l64]=tv7B; s_pi[1][7][l64]=(unsigned short)ti7B;
        s_pv[1][8][l64]=tv8B; s_pi[1][8][l64]=(unsigned short)ti8B;
    }
    __syncthreads();
    if (ch >= 2) return;

    if (ch == 0) {
        const float tvA[KK] = {tv0A,tv1A,tv2A,tv3A,tv4A,tv5A,tv6A,tv7A,tv8A};
        const int   tiA[KK] = {ti0A,ti1A,ti2A,ti3A,ti4A,ti5A,ti6A,ti7A,ti8A};
        EPILOGUE(tvA, tiA, piA, pj)
    } else {
        float tvH[KK]; int tiH[KK];
        #pragma unroll
        for (int k = 0; k < KK; ++k) {
            tvH[k] = s_pv[1][k][l64];
            tiH[k] = (int)s_pi[1][k][l64];
        }
        EPILOGUE(tvH, tiH, piB, pj)
    }
}

// ============================================================
// Fallback: round-1 fused kernel (no workspace needed).
// ============================================================
__global__ __launch_bounds__(256) void gnn_fused(
    const float* __restrict__ x_in, const float* __restrict__ Wf,
    const float* __restrict__ bf,   const float* __restrict__ Wp,
    const float* __restrict__ bp,   const float* __restrict__ W1,
    const float* __restrict__ b1,   const float* __restrict__ W2,
    const float* __restrict__ b2,   const float* __restrict__ sigma_p,
    const float* __restrict__ alpha_p, float* __restrict__ y)
{
    __shared__ float s_xf[NPIX][CF];
    __shared__ float s_xn[NPIX][CF];
    __shared__ float s_W[CC * CF];
    __shared__ float s_table[451];
    __shared__ float s_bias[CC];

    const int bpi = blockIdx.x;
    const int bb  = bpi / 49;
    const int ssb = bpi % 49;
    const int s1  = ssb / 7, s2 = ssb % 7;
    const int tid = threadIdx.x;
    const int pi  = tid >> 4, pj = tid & 15;
    const int gy  = s1 * 16 + pi, gx = s2 * 16 + pj;

    const float alpha = alpha_p[0];
    const float oma   = 1.0f - alpha;
    const float sig   = sigma_p[0];
    const float denom = 2.0f * sig * sig;

    for (int t = tid; t < CF * CC; t += NPIX) s_W[t] = Wf[t];
    if (tid < CF) s_bias[tid] = bf[tid];
    for (int t = tid; t < 451; t += NPIX) {
        float dd = sqrtf((float)t);
        s_table[t] = expf((-(dd * dd)) / denom);
    }
    float W1r[8], b1r[4], W2r[4];
    #pragma unroll
    for (int h = 0; h < 8; ++h) W1r[h] = W1[h];
    #pragma unroll
    for (int h = 0; h < 4; ++h) { b1r[h] = b1[h]; W2r[h] = W2[h]; }
    const float b2r = b2[0];
    __syncthreads();

    const float* xb = x_in + (size_t)bb * CC * HWQ + (size_t)gy * WWQ + gx;
    float fv[CF];
    #pragma unroll
    for (int o = 0; o < CF; ++o) fv[o] = 0.0f;
    for (int c = 0; c < CC; ++c) {
        float xv = xb[(size_t)c * HWQ];
        #pragma unroll
        for (int o = 0; o < CF; ++o)
            fv[o] = fmaf(xv, s_W[o * CC + c], fv[o]);
    }
    #pragma unroll
    for (int o = 0; o < CF; ++o) fv[o] += s_bias[o];

    float ss2 = 0.0f;
    #pragma unroll
    for (int o = 0; o < CF; ++o) ss2 = fmaf(fv[o], fv[o], ss2);
    float nrm = fmaxf(sqrtf(ss2), 1e-8f);

    float xnr[CF];
    #pragma unroll
    for (int o = 0; o < CF; ++o) {
        xnr[o] = fv[o] / nrm;
        s_xf[tid][o] = fv[o];
        s_xn[tid][o] = xnr[o];
    }
    __syncthreads();

    float tv[KK]; int ti[KK];
    #pragma unroll
    for (int k = 0; k < KK; ++k) { tv[k] = -INFINITY; ti[k] = 0; }

    for (int m = 0; m < NPIX; ++m) {
        const float4* xm4 = reinterpret_cast<const float4*>(&s_xn[m][0]);
        float4 a0 = xm4[0], a1 = xm4[1], a2 = xm4[2], a3 = xm4[3];
        float dot = 0.0f;
        dot = fmaf(xnr[0],  a0.x, dot); dot = fmaf(xnr[1],  a0.y, dot);
        dot = fmaf(xnr[2],  a0.z, dot); dot = fmaf(xnr[3],  a0.w, dot);
        dot = fmaf(xnr[4],  a1.x, dot); dot = fmaf(xnr[5],  a1.y, dot);
        dot = fmaf(xnr[6],  a1.z, dot); dot = fmaf(xnr[7],  a1.w, dot);
        dot = fmaf(xnr[8],  a2.x, dot); dot = fmaf(xnr[9],  a2.y, dot);
        dot = fmaf(xnr[10], a2.z, dot); dot = fmaf(xnr[11], a2.w, dot);
        dot = fmaf(xnr[12], a3.x, dot); dot = fmaf(xnr[13], a3.y, dot);
        dot = fmaf(xnr[14], a3.z, dot); dot = fmaf(xnr[15], a3.w, dot);

        int di = pi - (m >> 4);
        int dj = pj - (m & 15);
        float sd = s_table[di * di + dj * dj];
        float comb = __fadd_rn(__fmul_rn(alpha, dot), __fmul_rn(oma, sd));

        if (comb > tv[KK - 1]) {
            float cv = comb; int ci = m;
            #pragma unroll
            for (int t = KK - 1; t >= 0; --t) {
                bool g = (cv > tv[t]);
                float ov = tv[t]; int oi = ti[t];
                if (g) {
                    if (t + 1 < KK) { tv[t + 1] = ov; ti[t + 1] = oi; }
                    tv[t] = cv; ti[t] = ci;
                }
            }
        }
    }

    float wk[KK];
    float wsum = 0.0f;
    #pragma unroll
    for (int k = 0; k < KK; ++k) {
        int m = ti[k];
        int di = pi - (m >> 4);
        int dj = pj - (m & 15);
        float sd = s_table[di * di + dj * dj];
        float sf = (tv[k] - __fmul_rn(oma, sd)) / alpha;
        float hsum = b2r;
        #pragma unroll
        for (int h = 0; h < 4; ++h) {
            float z  = fmaf(sf, W1r[2 * h], fmaf(sd, W1r[2 * h + 1], b1r[h]));
            float sg = 1.0f / (1.0f + expf(-z));
            hsum = fmaf(z * sg, W2r[h], hsum);
        }
        float wg = 1.0f / (1.0f + expf(-hsum));
        wk[k] = wg;
        wsum += wg;
    }
    wsum += 1e-12f;

    float outv[CF];
    #pragma unroll
    for (int o = 0; o < CF; ++o) outv[o] = 0.0f;
    #pragma unroll
    for (int k = 0; k < KK; ++k) {
        float wn = wk[k] / wsum;
        int m = ti[k];
        const float4* xf4 = reinterpret_cast<const float4*>(&s_xf[m][0]);
        float4 m0 = xf4[0], m1 = xf4[1], m2 = xf4[2], m3 = xf4[3];
        outv[0]  = fmaf(wn, m0.x, outv[0]);  outv[1]  = fmaf(wn, m0.y, outv[1]);
        outv[2]  = fmaf(wn, m0.z, outv[2]);  outv[3]  = fmaf(wn, m0.w, outv[3]);
        outv[4]  = fmaf(wn, m1.x, outv[4]);  outv[5]  = fmaf(wn, m1.y, outv[5]);
        outv[6]  = fmaf(wn, m1.z, outv[6]);  outv[7]  = fmaf(wn, m1.w, outv[7]);
        outv[8]  = fmaf(wn, m2.x, outv[8]);  outv[9]  = fmaf(wn, m2.y, outv[9]);
        outv[10] = fmaf(wn, m2.z, outv[10]); outv[11] = fmaf(wn, m2.w, outv[11]);
        outv[12] = fmaf(wn, m3.x, outv[12]); outv[13] = fmaf(wn, m3.y, outv[13]);
        outv[14] = fmaf(wn, m3.z, outv[14]); outv[15] = fmaf(wn, m3.w, outv[15]);
    }

    __syncthreads();
    for (int t = tid; t < CC * CF; t += NPIX) s_W[t] = Wp[t];
    if (tid < CC) s_bias[tid] = bp[tid];
    __syncthreads();

    float* yb = y + (size_t)bb * CC * HWQ + (size_t)gy * WWQ + gx;
    for (int o = 0; o < CC; ++o) {
        float acc = 0.0f;
        #pragma unroll
        for (int c = 0; c < CF; ++c)
            acc = fmaf(outv[c], s_W[o * CF + c], acc);
        yb[(size_t)o * HWQ] = acc + s_bias[o];
    }
}

extern "C" void kernel_launch(void* const* d_in, const int* in_sizes, int n_in,
                              void* d_out, int out_size, void* d_ws, size_t ws_size,
                              hipStream_t stream) {
    const float* x_in  = (const float*)d_in[0];
    const float* Wf    = (const float*)d_in[1];
    const float* bf    = (const float*)d_in[2];
    const float* Wp    = (const float*)d_in[3];
    const float* bp    = (const float*)d_in[4];
    const float* W1    = (const float*)d_in[5];
    const float* b1    = (const float*)d_in[6];
    const float* W2    = (const float*)d_in[7];
    const float* b2    = (const float*)d_in[8];
    const float* sigma = (const float*)d_in[9];
    const float* alpha = (const float*)d_in[10];
    float* y = (float*)d_out;

    const size_t need = (size_t)(NROWS * (CF + 1)) * sizeof(float);
    if (ws_size >= need) {
        float* xn_g  = (float*)d_ws;
        float* nrm_g = xn_g + (size_t)NROWS * CF;
        feat_k<<<3136, 64, 0, stream>>>(x_in, Wf, bf, xn_g, nrm_g);
        gnn_split<<<NTILE * 2, 256, 0, stream>>>(xn_g, nrm_g, Wp, bp, W1, b1,
                                                 W2, b2, sigma, alpha, y);
    } else {
        gnn_fused<<<NTILE, NPIX, 0, stream>>>(x_in, Wf, bf, Wp, bp, W1, b1, W2,
                                              b2, sigma, alpha, y);
    }
}

// Round 14
// 151.410 us; speedup vs baseline: 1.2524x; 1.2524x over previous
//
#include <hip/hip_runtime.h>
#include <math.h>

// B=16, C=64, H=W=112, WS=7 -> 784 tiles of 16x16 pixels
#define CC    64
#define CF    16
#define NPIX  256
#define KK    9
#define HWQ   12544
#define WWQ   112
#define NTILE 784
#define NROWS (NTILE * NPIX)   // 200704

// ============================================================
// Kernel 1: per-pixel features f = Wf@x + bf, normalize.
// ============================================================
__global__ __launch_bounds__(64, 4) void feat_k(
    const float* __restrict__ x_in, const float* __restrict__ Wf,
    const float* __restrict__ bf,
    float* __restrict__ xn_g, float* __restrict__ nrm_g)
{
    __shared__ float s_Wt[CC * CF];   // transposed [c][o]
    __shared__ float s_bf[CF];
    const int tid = threadIdx.x;
    for (int idx = tid; idx < CC * CF; idx += 64) {
        int c = idx >> 4, o = idx & 15;
        s_Wt[idx] = Wf[o * CC + c];
    }
    if (tid < CF) s_bf[tid] = bf[tid];
    __syncthreads();

    const int p    = blockIdx.x * 64 + tid;
    const int tile = p >> 8, pix = p & 255;
    const int bb = tile / 49, ssb = tile % 49;
    const int s1 = ssb / 7, s2 = ssb % 7;
    const int gy = s1 * 16 + (pix >> 4), gx = s2 * 16 + (pix & 15);
    const float* xb = x_in + (size_t)bb * CC * HWQ + (size_t)gy * WWQ + gx;

    float fv[CF];
    #pragma unroll
    for (int o = 0; o < CF; ++o) fv[o] = 0.0f;
    #pragma unroll 8
    for (int c = 0; c < CC; ++c) {
        float xv = xb[(size_t)c * HWQ];
        const float4* w4 = reinterpret_cast<const float4*>(&s_Wt[c << 4]);
        float4 w0 = w4[0], w1 = w4[1], w2 = w4[2], w3 = w4[3];
        fv[0]  = fmaf(xv, w0.x, fv[0]);  fv[1]  = fmaf(xv, w0.y, fv[1]);
        fv[2]  = fmaf(xv, w0.z, fv[2]);  fv[3]  = fmaf(xv, w0.w, fv[3]);
        fv[4]  = fmaf(xv, w1.x, fv[4]);  fv[5]  = fmaf(xv, w1.y, fv[5]);
        fv[6]  = fmaf(xv, w1.z, fv[6]);  fv[7]  = fmaf(xv, w1.w, fv[7]);
        fv[8]  = fmaf(xv, w2.x, fv[8]);  fv[9]  = fmaf(xv, w2.y, fv[9]);
        fv[10] = fmaf(xv, w2.z, fv[10]); fv[11] = fmaf(xv, w2.w, fv[11]);
        fv[12] = fmaf(xv, w3.x, fv[12]); fv[13] = fmaf(xv, w3.y, fv[13]);
        fv[14] = fmaf(xv, w3.z, fv[14]); fv[15] = fmaf(xv, w3.w, fv[15]);
    }
    #pragma unroll
    for (int o = 0; o < CF; ++o) fv[o] += s_bf[o];

    float ss2 = 0.0f;
    #pragma unroll
    for (int o = 0; o < CF; ++o) ss2 = fmaf(fv[o], fv[o], ss2);
    float nrm = fmaxf(sqrtf(ss2), 1e-8f);

    float xn[CF];
    #pragma unroll
    for (int o = 0; o < CF; ++o) xn[o] = fv[o] / nrm;

    float4* dst = reinterpret_cast<float4*>(xn_g + (size_t)p * CF);
    dst[0] = make_float4(xn[0],  xn[1],  xn[2],  xn[3]);
    dst[1] = make_float4(xn[4],  xn[5],  xn[6],  xn[7]);
    dst[2] = make_float4(xn[8],  xn[9],  xn[10], xn[11]);
    dst[3] = make_float4(xn[12], xn[13], xn[14], xn[15]);
    nrm_g[p] = nrm;
}

// ---------------- shared scan machinery ----------------
#define DOT16(dot, X, a0, a1, a2, a3)                                \
    dot = fmaf(X[0],  (a0).x, dot); dot = fmaf(X[1],  (a0).y, dot);  \
    dot = fmaf(X[2],  (a0).z, dot); dot = fmaf(X[3],  (a0).w, dot);  \
    dot = fmaf(X[4],  (a1).x, dot); dot = fmaf(X[5],  (a1).y, dot);  \
    dot = fmaf(X[6],  (a1).z, dot); dot = fmaf(X[7],  (a1).w, dot);  \
    dot = fmaf(X[8],  (a2).x, dot); dot = fmaf(X[9],  (a2).y, dot);  \
    dot = fmaf(X[10], (a2).z, dot); dot = fmaf(X[11], (a2).w, dot);  \
    dot = fmaf(X[12], (a3).x, dot); dot = fmaf(X[13], (a3).y, dot);  \
    dot = fmaf(X[14], (a3).z, dot); dot = fmaf(X[15], (a3).w, dot);

// guard-free sorted top-9 insert on suffixed state (tv0S..tv8S / ti0S..ti8S);
// strict '>' keeps lower index on ties, matching lax.top_k.
#define TOP9_INS(S, cv, ci) {                                        \
    const bool g0 = (cv) > tv0##S; const bool g1 = (cv) > tv1##S;    \
    const bool g2 = (cv) > tv2##S; const bool g3 = (cv) > tv3##S;    \
    const bool g4 = (cv) > tv4##S; const bool g5 = (cv) > tv5##S;    \
    const bool g6 = (cv) > tv6##S; const bool g7 = (cv) > tv7##S;    \
    const bool g8 = (cv) > tv8##S;                                   \
    const float nv0 = g0 ? (cv) : tv0##S;                            \
    const float nv1 = __builtin_amdgcn_fmed3f((cv), tv0##S, tv1##S); \
    const float nv2 = __builtin_amdgcn_fmed3f((cv), tv1##S, tv2##S); \
    const float nv3 = __builtin_amdgcn_fmed3f((cv), tv2##S, tv3##S); \
    const float nv4 = __builtin_amdgcn_fmed3f((cv), tv3##S, tv4##S); \
    const float nv5 = __builtin_amdgcn_fmed3f((cv), tv4##S, tv5##S); \
    const float nv6 = __builtin_amdgcn_fmed3f((cv), tv5##S, tv6##S); \
    const float nv7 = __builtin_amdgcn_fmed3f((cv), tv6##S, tv7##S); \
    const float nv8 = __builtin_amdgcn_fmed3f((cv), tv7##S, tv8##S); \
    const int nt0 = g0 ? (ci) : ti0##S;                              \
    const int nt1 = g0 ? ti0##S : (g1 ? (ci) : ti1##S);              \
    const int nt2 = g1 ? ti1##S : (g2 ? (ci) : ti2##S);              \
    const int nt3 = g2 ? ti2##S : (g3 ? (ci) : ti3##S);              \
    const int nt4 = g3 ? ti3##S : (g4 ? (ci) : ti4##S);              \
    const int nt5 = g4 ? ti4##S : (g5 ? (ci) : ti5##S);              \
    const int nt6 = g5 ? ti5##S : (g6 ? (ci) : ti6##S);              \
    const int nt7 = g6 ? ti6##S : (g7 ? (ci) : ti7##S);              \
    const int nt8 = g7 ? ti7##S : (g8 ? (ci) : ti8##S);              \
    tv0##S = nv0; tv1##S = nv1; tv2##S = nv2; tv3##S = nv3;          \
    tv4##S = nv4; tv5##S = nv5; tv6##S = nv6; tv7##S = nv7;          \
    tv8##S = nv8;                                                    \
    ti0##S = nt0; ti1##S = nt1; ti2##S = nt2; ti3##S = nt3;          \
    ti4##S = nt4; ti5##S = nt5; ti6##S = nt6; ti7##S = nt7;          \
    ti8##S = nt8; }

// one candidate, two rows (A,B): 4 ds_read_b128 feed 2 dots.
// insert index is the GLOBAL candidate id (no split, no globalization).
#define SIM_ITER2(MJ) {                                              \
    const int m = mbase + (MJ);                                      \
    const float4* xm4 =                                              \
        reinterpret_cast<const float4*>(&s_xn[m][0]);                \
    const float4 a0 = xm4[0], a1 = xm4[1], a2 = xm4[2], a3 = xm4[3]; \
    float dotA = 0.0f, dotB = 0.0f;                                  \
    DOT16(dotA, xnrA, a0, a1, a2, a3);                               \
    DOT16(dotB, xnrB, a0, a1, a2, a3);                               \
    const int dj = pj - (MJ);                                        \
    const int dj2 = dj * dj;                                         \
    const float sA = s_tabA[d2iA + dj2];                             \
    const float sB = s_tabA[d2iB + dj2];                             \
    const float combA = __fadd_rn(__fmul_rn(alpha, dotA), sA);       \
    const float combB = __fadd_rn(__fmul_rn(alpha, dotB), sB);       \
    TOP9_INS(A, combA, m)                                            \
    TOP9_INS(B, combB, m) }

#define SIM_ROW16_2()                                                \
        SIM_ITER2(0)  SIM_ITER2(1)  SIM_ITER2(2)  SIM_ITER2(3)       \
        SIM_ITER2(4)  SIM_ITER2(5)  SIM_ITER2(6)  SIM_ITER2(7)       \
        SIM_ITER2(8)  SIM_ITER2(9)  SIM_ITER2(10) SIM_ITER2(11)      \
        SIM_ITER2(12) SIM_ITER2(13) SIM_ITER2(14) SIM_ITER2(15)

// full per-row epilogue: edge MLP + aggregate + project + store
#define EPILOGUE(TV, TI, PI, PJ) {                                   \
    float wk[KK]; float wsum = 0.0f;                                 \
    _Pragma("unroll")                                                \
    for (int k = 0; k < KK; ++k) {                                   \
        int m = TI[k];                                               \
        int di = (PI) - (m >> 4);                                    \
        int dj = (PJ) - (m & 15);                                    \
        float sd = s_tab[di * di + dj * dj];                         \
        float sf = (TV[k] - __fmul_rn(oma, sd)) / alpha;             \
        float hsum = b2r;                                            \
        _Pragma("unroll")                                            \
        for (int h = 0; h < 4; ++h) {                                \
            float z  = fmaf(sf, W1r[2*h], fmaf(sd, W1r[2*h+1], b1r[h])); \
            float sg = 1.0f / (1.0f + expf(-z));                     \
            hsum = fmaf(z * sg, W2r[h], hsum);                       \
        }                                                            \
        float wg = 1.0f / (1.0f + expf(-hsum));                      \
        wk[k] = wg; wsum += wg;                                      \
    }                                                                \
    wsum += 1e-12f;                                                  \
    float outv[CF];                                                  \
    _Pragma("unroll")                                                \
    for (int o = 0; o < CF; ++o) outv[o] = 0.0f;                     \
    _Pragma("unroll")                                                \
    for (int k = 0; k < KK; ++k) {                                   \
        const int m = TI[k];                                         \
        const float wnm = (wk[k] / wsum) * s_nrm[m];                 \
        const float4* xf4 = reinterpret_cast<const float4*>(&s_xn[m][0]); \
        float4 m0 = xf4[0], m1 = xf4[1], m2 = xf4[2], m3 = xf4[3];   \
        outv[0]  = fmaf(wnm, m0.x, outv[0]);  outv[1]  = fmaf(wnm, m0.y, outv[1]);  \
        outv[2]  = fmaf(wnm, m0.z, outv[2]);  outv[3]  = fmaf(wnm, m0.w, outv[3]);  \
        outv[4]  = fmaf(wnm, m1.x, outv[4]);  outv[5]  = fmaf(wnm, m1.y, outv[5]);  \
        outv[6]  = fmaf(wnm, m1.z, outv[6]);  outv[7]  = fmaf(wnm, m1.w, outv[7]);  \
        outv[8]  = fmaf(wnm, m2.x, outv[8]);  outv[9]  = fmaf(wnm, m2.y, outv[9]);  \
        outv[10] = fmaf(wnm, m2.z, outv[10]); outv[11] = fmaf(wnm, m2.w, outv[11]); \
        outv[12] = fmaf(wnm, m3.x, outv[12]); outv[13] = fmaf(wnm, m3.y, outv[13]); \
        outv[14] = fmaf(wnm, m3.z, outv[14]); outv[15] = fmaf(wnm, m3.w, outv[15]); \
    }                                                                \
    const int gy = s1 * 16 + (PI), gx = s2 * 16 + (PJ);              \
    float* yb = y + (size_t)bb * CC * HWQ + (size_t)gy * WWQ + gx;   \
    _Pragma("unroll 4")                                              \
    for (int o = 0; o < CC; ++o) {                                   \
        const float4* w4 = reinterpret_cast<const float4*>(&Wp[o * CF]); \
        float4 w0 = w4[0], w1 = w4[1], w2 = w4[2], w3 = w4[3];       \
        float acc = 0.0f;                                            \
        acc = fmaf(outv[0],  w0.x, acc); acc = fmaf(outv[1],  w0.y, acc); \
        acc = fmaf(outv[2],  w0.z, acc); acc = fmaf(outv[3],  w0.w, acc); \
        acc = fmaf(outv[4],  w1.x, acc); acc = fmaf(outv[5],  w1.y, acc); \
        acc = fmaf(outv[6],  w1.z, acc); acc = fmaf(outv[7],  w1.w, acc); \
        acc = fmaf(outv[8],  w2.x, acc); acc = fmaf(outv[9],  w2.y, acc); \
        acc = fmaf(outv[10], w2.z, acc); acc = fmaf(outv[11], w2.w, acc); \
        acc = fmaf(outv[12], w3.x, acc); acc = fmaf(outv[13], w3.y, acc); \
        acc = fmaf(outv[14], w3.z, acc); acc = fmaf(outv[15], w3.w, acc); \
        yb[(size_t)o * HWQ] = acc + bp[o];                           \
    } }

// ============================================================
// Kernel 2: one block per tile, 128 threads (2 waves), 2 rows/thread
// (rA=tid, rB=tid+128: same pj, pi differs by 8). Full 256-candidate
// scan per thread -> NO merge, no partial slots, no idle waves.
// LDS 20.6 KB -> 7 blocks/CU: all 784 blocks co-resident.
// ============================================================
__global__ __launch_bounds__(128, 2) void gnn_2row(
    const float* __restrict__ xn_g, const float* __restrict__ nrm_g,
    const float* __restrict__ Wp,   const float* __restrict__ bp,
    const float* __restrict__ W1,   const float* __restrict__ b1,
    const float* __restrict__ W2,   const float* __restrict__ b2,
    const float* __restrict__ sigma_p, const float* __restrict__ alpha_p,
    float* __restrict__ y)
{
    __shared__ float s_xn[NPIX][CF];   // 16 KB tile features
    __shared__ float s_nrm[NPIX];      // 1 KB
    __shared__ float s_tab[451];       // raw exp(-d^2/(2 sigma^2))
    __shared__ float s_tabA[451];      // (1-alpha) * table

    const int tile = blockIdx.x;
    const int bb = tile / 49, ssb = tile % 49;
    const int s1 = ssb / 7, s2 = ssb % 7;
    const int tid = threadIdx.x;       // 0..127

    const float alpha = alpha_p[0];
    const float oma   = 1.0f - alpha;
    const float sig   = sigma_p[0];
    const float denom = 2.0f * sig * sig;

    for (int t = tid; t < 451; t += 128) {
        float dd = sqrtf((float)t);
        float v  = expf((-(dd * dd)) / denom);
        s_tab[t]  = v;
        s_tabA[t] = __fmul_rn(oma, v);
    }
    const float* xt = xn_g + (size_t)tile * NPIX * CF;
    {
        const float4* src = reinterpret_cast<const float4*>(xt);
        float4*       dst = reinterpret_cast<float4*>(&s_xn[0][0]);
        #pragma unroll
        for (int i = 0; i < 8; ++i) dst[tid + i * 128] = src[tid + i * 128];
        const float* nsrc = nrm_g + (size_t)tile * NPIX;
        s_nrm[tid]       = nsrc[tid];
        s_nrm[tid + 128] = nsrc[tid + 128];
    }
    float W1r[8], b1r[4], W2r[4];
    #pragma unroll
    for (int h = 0; h < 8; ++h) W1r[h] = W1[h];
    #pragma unroll
    for (int h = 0; h < 4; ++h) { b1r[h] = b1[h]; W2r[h] = W2[h]; }
    const float b2r = b2[0];
    __syncthreads();

    const int rA  = tid;               // rows owned by this thread
    const int rB  = tid + 128;
    const int piA = rA >> 4;           // 0..7
    const int piB = piA + 8;           // 8..15
    const int pj  = rA & 15;           // same for both rows

    float xnrA[CF], xnrB[CF];
    {
        const float4* xa = reinterpret_cast<const float4*>(&s_xn[rA][0]);
        float4 a0 = xa[0], a1 = xa[1], a2 = xa[2], a3 = xa[3];
        xnrA[0]=a0.x;  xnrA[1]=a0.y;  xnrA[2]=a0.z;  xnrA[3]=a0.w;
        xnrA[4]=a1.x;  xnrA[5]=a1.y;  xnrA[6]=a1.z;  xnrA[7]=a1.w;
        xnrA[8]=a2.x;  xnrA[9]=a2.y;  xnrA[10]=a2.z; xnrA[11]=a2.w;
        xnrA[12]=a3.x; xnrA[13]=a3.y; xnrA[14]=a3.z; xnrA[15]=a3.w;
        const float4* xb4 = reinterpret_cast<const float4*>(&s_xn[rB][0]);
        float4 b0 = xb4[0], b1v = xb4[1], b2v = xb4[2], b3 = xb4[3];
        xnrB[0]=b0.x;  xnrB[1]=b0.y;  xnrB[2]=b0.z;  xnrB[3]=b0.w;
        xnrB[4]=b1v.x; xnrB[5]=b1v.y; xnrB[6]=b1v.z; xnrB[7]=b1v.w;
        xnrB[8]=b2v.x; xnrB[9]=b2v.y; xnrB[10]=b2v.z; xnrB[11]=b2v.w;
        xnrB[12]=b3.x; xnrB[13]=b3.y; xnrB[14]=b3.z; xnrB[15]=b3.w;
    }

    float tv0A,tv1A,tv2A,tv3A,tv4A,tv5A,tv6A,tv7A,tv8A;
    int   ti0A,ti1A,ti2A,ti3A,ti4A,ti5A,ti6A,ti7A,ti8A;
    float tv0B,tv1B,tv2B,tv3B,tv4B,tv5B,tv6B,tv7B,tv8B;
    int   ti0B,ti1B,ti2B,ti3B,ti4B,ti5B,ti6B,ti7B,ti8B;
    tv0A=tv1A=tv2A=tv3A=tv4A=tv5A=tv6A=tv7A=tv8A = -INFINITY;
    ti0A=ti1A=ti2A=ti3A=ti4A=ti5A=ti6A=ti7A=ti8A = 0;
    tv0B=tv1B=tv2B=tv3B=tv4B=tv5B=tv6B=tv7B=tv8B = -INFINITY;
    ti0B=ti1B=ti2B=ti3B=ti4B=ti5B=ti6B=ti7B=ti8B = 0;

    // full scan: mi = 0..15, sequential m order matches reference
    #pragma unroll 1
    for (int mi = 0; mi < 16; ++mi) {
        const int diA   = piA - mi;
        const int diB   = piB - mi;
        const int d2iA  = diA * diA;
        const int d2iB  = diB * diB;
        const int mbase = mi << 4;
        SIM_ROW16_2()
    }

    const float tvA[KK] = {tv0A,tv1A,tv2A,tv3A,tv4A,tv5A,tv6A,tv7A,tv8A};
    const int   tiA[KK] = {ti0A,ti1A,ti2A,ti3A,ti4A,ti5A,ti6A,ti7A,ti8A};
    const float tvB[KK] = {tv0B,tv1B,tv2B,tv3B,tv4B,tv5B,tv6B,tv7B,tv8B};
    const int   tiB[KK] = {ti0B,ti1B,ti2B,ti3B,ti4B,ti5B,ti6B,ti7B,ti8B};

    EPILOGUE(tvA, tiA, piA, pj)
    EPILOGUE(tvB, tiB, piB, pj)
}

// ============================================================
// Fallback: round-1 fused kernel (no workspace needed).
// ============================================================
__global__ __launch_bounds__(256) void gnn_fused(
    const float* __restrict__ x_in, const float* __restrict__ Wf,
    const float* __restrict__ bf,   const float* __restrict__ Wp,
    const float* __restrict__ bp,   const float* __restrict__ W1,
    const float* __restrict__ b1,   const float* __restrict__ W2,
    const float* __restrict__ b2,   const float* __restrict__ sigma_p,
    const float* __restrict__ alpha_p, float* __restrict__ y)
{
    __shared__ float s_xf[NPIX][CF];
    __shared__ float s_xn[NPIX][CF];
    __shared__ float s_W[CC * CF];
    __shared__ float s_table[451];
    __shared__ float s_bias[CC];

    const int bpi = blockIdx.x;
    const int bb  = bpi / 49;
    const int ssb = bpi % 49;
    const int s1  = ssb / 7, s2 = ssb % 7;
    const int tid = threadIdx.x;
    const int pi  = tid >> 4, pj = tid & 15;
    const int gy  = s1 * 16 + pi, gx = s2 * 16 + pj;

    const float alpha = alpha_p[0];
    const float oma   = 1.0f - alpha;
    const float sig   = sigma_p[0];
    const float denom = 2.0f * sig * sig;

    for (int t = tid; t < CF * CC; t += NPIX) s_W[t] = Wf[t];
    if (tid < CF) s_bias[tid] = bf[tid];
    for (int t = tid; t < 451; t += NPIX) {
        float dd = sqrtf((float)t);
        s_table[t] = expf((-(dd * dd)) / denom);
    }
    float W1r[8], b1r[4], W2r[4];
    #pragma unroll
    for (int h = 0; h < 8; ++h) W1r[h] = W1[h];
    #pragma unroll
    for (int h = 0; h < 4; ++h) { b1r[h] = b1[h]; W2r[h] = W2[h]; }
    const float b2r = b2[0];
    __syncthreads();

    const float* xb = x_in + (size_t)bb * CC * HWQ + (size_t)gy * WWQ + gx;
    float fv[CF];
    #pragma unroll
    for (int o = 0; o < CF; ++o) fv[o] = 0.0f;
    for (int c = 0; c < CC; ++c) {
        float xv = xb[(size_t)c * HWQ];
        #pragma unroll
        for (int o = 0; o < CF; ++o)
            fv[o] = fmaf(xv, s_W[o * CC + c], fv[o]);
    }
    #pragma unroll
    for (int o = 0; o < CF; ++o) fv[o] += s_bias[o];

    float ss2 = 0.0f;
    #pragma unroll
    for (int o = 0; o < CF; ++o) ss2 = fmaf(fv[o], fv[o], ss2);
    float nrm = fmaxf(sqrtf(ss2), 1e-8f);

    float xnr[CF];
    #pragma unroll
    for (int o = 0; o < CF; ++o) {
        xnr[o] = fv[o] / nrm;
        s_xf[tid][o] = fv[o];
        s_xn[tid][o] = xnr[o];
    }
    __syncthreads();

    float tv[KK]; int ti[KK];
    #pragma unroll
    for (int k = 0; k < KK; ++k) { tv[k] = -INFINITY; ti[k] = 0; }

    for (int m = 0; m < NPIX; ++m) {
        const float4* xm4 = reinterpret_cast<const float4*>(&s_xn[m][0]);
        float4 a0 = xm4[0], a1 = xm4[1], a2 = xm4[2], a3 = xm4[3];
        float dot = 0.0f;
        dot = fmaf(xnr[0],  a0.x, dot); dot = fmaf(xnr[1],  a0.y, dot);
        dot = fmaf(xnr[2],  a0.z, dot); dot = fmaf(xnr[3],  a0.w, dot);
        dot = fmaf(xnr[4],  a1.x, dot); dot = fmaf(xnr[5],  a1.y, dot);
        dot = fmaf(xnr[6],  a1.z, dot); dot = fmaf(xnr[7],  a1.w, dot);
        dot = fmaf(xnr[8],  a2.x, dot); dot = fmaf(xnr[9],  a2.y, dot);
        dot = fmaf(xnr[10], a2.z, dot); dot = fmaf(xnr[11], a2.w, dot);
        dot = fmaf(xnr[12], a3.x, dot); dot = fmaf(xnr[13], a3.y, dot);
        dot = fmaf(xnr[14], a3.z, dot); dot = fmaf(xnr[15], a3.w, dot);

        int di = pi - (m >> 4);
        int dj = pj - (m & 15);
        float sd = s_table[di * di + dj * dj];
        float comb = __fadd_rn(__fmul_rn(alpha, dot), __fmul_rn(oma, sd));

        if (comb > tv[KK - 1]) {
            float cv = comb; int ci = m;
            #pragma unroll
            for (int t = KK - 1; t >= 0; --t) {
                bool g = (cv > tv[t]);
                float ov = tv[t]; int oi = ti[t];
                if (g) {
                    if (t + 1 < KK) { tv[t + 1] = ov; ti[t + 1] = oi; }
                    tv[t] = cv; ti[t] = ci;
                }
            }
        }
    }

    float wk[KK];
    float wsum = 0.0f;
    #pragma unroll
    for (int k = 0; k < KK; ++k) {
        int m = ti[k];
        int di = pi - (m >> 4);
        int dj = pj - (m & 15);
        float sd = s_table[di * di + dj * dj];
        float sf = (tv[k] - __fmul_rn(oma, sd)) / alpha;
        float hsum = b2r;
        #pragma unroll
        for (int h = 0; h < 4; ++h) {
            float z  = fmaf(sf, W1r[2 * h], fmaf(sd, W1r[2 * h + 1], b1r[h]));
            float sg = 1.0f / (1.0f + expf(-z));
            hsum = fmaf(z * sg, W2r[h], hsum);
        }
        float wg = 1.0f / (1.0f + expf(-hsum));
        wk[k] = wg;
        wsum += wg;
    }
    wsum += 1e-12f;

    float outv[CF];
    #pragma unroll
    for (int o = 0; o < CF; ++o) outv[o] = 0.0f;
    #pragma unroll
    for (int k = 0; k < KK; ++k) {
        float wn = wk[k] / wsum;
        int m = ti[k];
        const float4* xf4 = reinterpret_cast<const float4*>(&s_xf[m][0]);
        float4 m0 = xf4[0], m1 = xf4[1], m2 = xf4[2], m3 = xf4[3];
        outv[0]  = fmaf(wn, m0.x, outv[0]);  outv[1]  = fmaf(wn, m0.y, outv[1]);
        outv[2]  = fmaf(wn, m0.z, outv[2]);  outv[3]  = fmaf(wn, m0.w, outv[3]);
        outv[4]  = fmaf(wn, m1.x, outv[4]);  outv[5]  = fmaf(wn, m1.y, outv[5]);
        outv[6]  = fmaf(wn, m1.z, outv[6]);  outv[7]  = fmaf(wn, m1.w, outv[7]);
        outv[8]  = fmaf(wn, m2.x, outv[8]);  outv[9]  = fmaf(wn, m2.y, outv[9]);
        outv[10] = fmaf(wn, m2.z, outv[10]); outv[11] = fmaf(wn, m2.w, outv[11]);
        outv[12] = fmaf(wn, m3.x, outv[12]); outv[13] = fmaf(wn, m3.y, outv[13]);
        outv[14] = fmaf(wn, m3.z, outv[14]); outv[15] = fmaf(wn, m3.w, outv[15]);
    }

    __syncthreads();
    for (int t = tid; t < CC * CF; t += NPIX) s_W[t] = Wp[t];
    if (tid < CC) s_bias[tid] = bp[tid];
    __syncthreads();

    float* yb = y + (size_t)bb * CC * HWQ + (size_t)gy * WWQ + gx;
    for (int o = 0; o < CC; ++o) {
        float acc = 0.0f;
        #pragma unroll
        for (int c = 0; c < CF; ++c)
            acc = fmaf(outv[c], s_W[o * CF + c], acc);
        yb[(size_t)o * HWQ] = acc + s_bias[o];
    }
}

extern "C" void kernel_launch(void* const* d_in, const int* in_sizes, int n_in,
                              void* d_out, int out_size, void* d_ws, size_t ws_size,
                              hipStream_t stream) {
    const float* x_in  = (const float*)d_in[0];
    const float* Wf    = (const float*)d_in[1];
    const float* bf    = (const float*)d_in[2];
    const float* Wp    = (const float*)d_in[3];
    const float* bp    = (const float*)d_in[4];
    const float* W1    = (const float*)d_in[5];
    const float* b1    = (const float*)d_in[6];
    const float* W2    = (const float*)d_in[7];
    const float* b2    = (const float*)d_in[8];
    const float* sigma = (const float*)d_in[9];
    const float* alpha = (const float*)d_in[10];
    float* y = (float*)d_out;

    const size_t need = (size_t)(NROWS * (CF + 1)) * sizeof(float);
    if (ws_size >= need) {
        float* xn_g  = (float*)d_ws;
        float* nrm_g = xn_g + (size_t)NROWS * CF;
        feat_k<<<3136, 64, 0, stream>>>(x_in, Wf, bf, xn_g, nrm_g);
        gnn_2row<<<NTILE, 128, 0, stream>>>(xn_g, nrm_g, Wp, bp, W1, b1,
                                            W2, b2, sigma, alpha, y);
    } else {
        gnn_fused<<<NTILE, NPIX, 0, stream>>>(x_in, Wf, bf, Wp, bp, W1, b1, W2,
                                              b2, sigma, alpha, y);
    }
}